// Round 5
// baseline (173.023 us; speedup 1.0000x reference)
//
#include <hip/hip_runtime.h>
#include <math.h>

#define B_DIM 4
#define S_DIM 4096
#define E_DIM 1024
#define A_DIM 64
#define M_TOT (B_DIM * S_DIM) /* 16384 */

typedef __bf16 v8bf __attribute__((ext_vector_type(8)));
typedef __bf16 v4bf __attribute__((ext_vector_type(4)));
typedef float  v4f  __attribute__((ext_vector_type(4)));

__device__ __forceinline__ v4f mfma16(v8bf a, v8bf b, v4f c) {
    return __builtin_amdgcn_mfma_f32_16x16x32_bf16(a, b, c, 0, 0, 0);
}

// ---------------------------------------------------------------------------
// Pre-pass: fp32 weights -> bf16 Wb[192][1024] (rows 0-63 K, 64-127 Q, 128-191 V).
// ---------------------------------------------------------------------------
__global__ __launch_bounds__(256) void wconv_kernel(
    const float* __restrict__ Wk, const float* __restrict__ Wq,
    const float* __restrict__ Wv, __bf16* __restrict__ Wb)
{
    const int i = blockIdx.x * 256 + threadIdx.x;   // float4 index, 49152 total
    const int w = i >> 14;
    const int off = (i & 16383) * 4;
    const float* s = ((w == 0) ? Wk : (w == 1) ? Wq : Wv) + off;
    float4 v = *(const float4*)s;
    v4bf o;
    o[0] = (__bf16)v.x; o[1] = (__bf16)v.y; o[2] = (__bf16)v.z; o[3] = (__bf16)v.w;
    *(v4bf*)(Wb + (size_t)w * 65536 + off) = o;
}

// ---------------------------------------------------------------------------
// Fused QKV projection v12: barrier-free streaming MFMA.
// Diagnosis (r2 counters + r3/r4 occupancy nulls): the per-K-chunk
// s_waitcnt vmcnt(0) drain before __syncthreads was the bottleneck — the
// documented m97 structural stall — and extra waves/blocks can't hide it
// because every wave stalls at its own drain with only ~12 MFMA/barrier.
// Fix: N=192 is so skinny that LDS staging is unnecessary.  Both MFMA
// fragments are loaded DIRECTLY per lane (algebraically identical bytes and
// identical k-accumulation order to the v8 LDS path -> bitwise-same result):
//   A-frag: X[(r0+mi*16+L)*1024 + c*32 + quad*8]  (2 x float4 fp32 -> cvt)
//   B-frag: Wb[(cbase+nt*16+L)*1024 + c*32 + quad*8]  (1 x 16B bf16)
// 512 blocks x 4 waves; block = 32 rows x 192 cols; 32 chunks of K=32;
// ZERO barriers / ZERO LDS in the k-loop -> the compiler software-pipelines
// loads across chunks (7 VMEM in flight/wave, ~56/CU at 8 waves/CU).
// X chunk-slices are L1-resident across the 4 waves; W is L2-resident.
// ---------------------------------------------------------------------------
__global__ __launch_bounds__(256) void qkv_proj_mfma(
    const float* __restrict__ X,
    const __bf16* __restrict__ Wb,   // [192][1024]
    __bf16* __restrict__ Kb,
    __bf16* __restrict__ Qb,
    __bf16* __restrict__ Vt)
{
    const int r0   = blockIdx.x * 32;
    const int w    = threadIdx.x >> 6;
    const int lane = threadIdx.x & 63;
    const int L    = lane & 15;
    const int quad = lane >> 4;
    const int cbase = w * 48;

    __shared__ __align__(16) float Tv[32][65];   // epilogue V-transpose only

    v4f acc[2][3]; // [mi][nt]
#pragma unroll
    for (int mi = 0; mi < 2; ++mi)
#pragma unroll
        for (int nt = 0; nt < 3; ++nt) acc[mi][nt] = (v4f){0.f, 0.f, 0.f, 0.f};

    const float* xbase0 = X + (size_t)(r0 + L) * E_DIM + quad * 8;
    const float* xbase1 = X + (size_t)(r0 + 16 + L) * E_DIM + quad * 8;
    const __bf16* wb0 = Wb + (size_t)(cbase + L) * E_DIM + quad * 8;

#pragma unroll 2
    for (int c = 0; c < 32; ++c) {
        // ---- A fragments: direct fp32 global loads + cvt ----
        v8bf afr[2];
#pragma unroll
        for (int mi = 0; mi < 2; ++mi) {
            const float* xp = (mi ? xbase1 : xbase0) + c * 32;
            float4 x0 = *(const float4*)xp;
            float4 x1 = *(const float4*)(xp + 4);
            afr[mi][0] = (__bf16)x0.x; afr[mi][1] = (__bf16)x0.y;
            afr[mi][2] = (__bf16)x0.z; afr[mi][3] = (__bf16)x0.w;
            afr[mi][4] = (__bf16)x1.x; afr[mi][5] = (__bf16)x1.y;
            afr[mi][6] = (__bf16)x1.z; afr[mi][7] = (__bf16)x1.w;
        }
        // ---- B fragments: direct bf16 global loads (L2-resident) ----
        v8bf bfr[3];
#pragma unroll
        for (int nt = 0; nt < 3; ++nt)
            bfr[nt] = *(const v8bf*)(wb0 + (size_t)nt * 16 * E_DIM + c * 32);
#pragma unroll
        for (int mi = 0; mi < 2; ++mi)
#pragma unroll
            for (int nt = 0; nt < 3; ++nt)
                acc[mi][nt] = mfma16(afr[mi], bfr[nt], acc[mi][nt]);
    }

    // ---- epilogue: K (cols<64), Q (<128, x1/8), V (->LDS transpose) ----
#pragma unroll
    for (int nt = 0; nt < 3; ++nt) {
        const int c0 = cbase + nt * 16; // wave-uniform; tiles never straddle
        if (c0 < 64) {
#pragma unroll
            for (int mi = 0; mi < 2; ++mi)
#pragma unroll
                for (int r = 0; r < 4; ++r)
                    Kb[(size_t)(r0 + mi * 16 + quad * 4 + r) * A_DIM + c0 + L] =
                        (__bf16)acc[mi][nt][r];
        } else if (c0 < 128) {
#pragma unroll
            for (int mi = 0; mi < 2; ++mi)
#pragma unroll
                for (int r = 0; r < 4; ++r)
                    Qb[(size_t)(r0 + mi * 16 + quad * 4 + r) * A_DIM + (c0 - 64) + L] =
                        (__bf16)(acc[mi][nt][r] * 0.125f);
        } else {
#pragma unroll
            for (int mi = 0; mi < 2; ++mi)
#pragma unroll
                for (int r = 0; r < 4; ++r)
                    Tv[mi * 16 + quad * 4 + r][(c0 - 128) + L] = acc[mi][nt][r];
        }
    }
    __syncthreads();

    // transposed V write: thread t -> V-col a = t>>2, s-eighth = t&3 (8 rows)
    {
        const int batch = r0 >> 12;
        const int s0    = r0 & 4095;
        const int a     = threadIdx.x >> 2;
        const int part  = threadIdx.x & 3;
        __bf16* vrow = Vt + (size_t)(batch * 64 + a) * S_DIM + s0 + part * 8;
        v8bf pk;
#pragma unroll
        for (int j = 0; j < 8; ++j)
            pk[j] = (__bf16)Tv[part * 8 + j][a];
        *(v8bf*)vrow = pk;
    }
}

// ---------------------------------------------------------------------------
// Causal flash attention v5 (round-1-verified, untouched this round):
// no split-K, no combine pass.  One 512-thread block (8 waves) per (b, qt);
// waves stride 8 over k-tiles; wave-private Pt scratch, no barriers in the
// k-loop; cross-wave l/O reduction in LDS; fp32 out written directly.
// ---------------------------------------------------------------------------
__global__ __launch_bounds__(512, 2) void attn_fused(
    const __bf16* __restrict__ Qb,
    const __bf16* __restrict__ Kb,
    const __bf16* __restrict__ Vt,
    float* __restrict__ out)
{
    const int b  = blockIdx.y;
    const int qt = blockIdx.x;              // 0..63

    const int w    = threadIdx.x >> 6;      // 0..7
    const int lane = threadIdx.x & 63;
    const int L    = lane & 15;
    const int quad = lane >> 4;

    __shared__ __align__(16) char smem[73728];
    __bf16 (*Pt)[64][72]   = (__bf16(*)[64][72])smem;          // [8][64][72] loop phase
    float*  red_l          = (float*)smem;                     // [8][64]   combine phase
    float (*red_o)[64][65] = (float(*)[64][65])(smem + 2048);  // [4][64][65]
    float*  invs           = (float*)(smem + 2048 + 66560);    // [64]

    v8bf qf[4][2];
#pragma unroll
    for (int ni = 0; ni < 4; ++ni)
#pragma unroll
        for (int ka = 0; ka < 2; ++ka)
            qf[ni][ka] = *(const v8bf*)(Qb +
                (size_t)(b * S_DIM + qt * 64 + ni * 16 + L) * A_DIM + ka * 32 + quad * 8);

    v4f acc_o[4][4];
#pragma unroll
    for (int i = 0; i < 4; ++i)
#pragma unroll
        for (int j = 0; j < 4; ++j) acc_o[i][j] = (v4f){0.f, 0.f, 0.f, 0.f};
    float lrun[4] = {0.f, 0.f, 0.f, 0.f};

    for (int kt = w; kt <= qt; kt += 8) {
        v8bf kf[4][2];
#pragma unroll
        for (int mi = 0; mi < 4; ++mi)
#pragma unroll
            for (int ka = 0; ka < 2; ++ka)
                kf[mi][ka] = *(const v8bf*)(Kb +
                    (size_t)(b * S_DIM + kt * 64 + mi * 16 + L) * A_DIM + ka * 32 + quad * 8);
        v8bf vf[4][2];
#pragma unroll
        for (int ma = 0; ma < 4; ++ma)
#pragma unroll
            for (int ki = 0; ki < 2; ++ki)
                vf[ma][ki] = *(const v8bf*)(Vt +
                    (size_t)(b * 64 + ma * 16 + L) * S_DIM + kt * 64 + ki * 32 + quad * 8);

        const bool diag = (kt == qt);

#pragma unroll
        for (int ni = 0; ni < 4; ++ni) {
            v4f s[4];
#pragma unroll
            for (int mi = 0; mi < 4; ++mi) s[mi] = (v4f){0.f, 0.f, 0.f, 0.f};
#pragma unroll
            for (int mi = 0; mi < 4; ++mi)
#pragma unroll
                for (int ka = 0; ka < 2; ++ka)
                    s[mi] = mfma16(kf[mi][ka], qf[ni][ka], s[mi]);

            float rs = 0.f;
#pragma unroll
            for (int mi = 0; mi < 4; ++mi) {
                v4bf p4;
#pragma unroll
                for (int r = 0; r < 4; ++r) {
                    const bool masked = diag && (mi * 16 + quad * 4 + r > ni * 16 + L);
                    const float p = masked ? 0.f : __expf(s[mi][r]);
                    rs += p;
                    p4[r] = (__bf16)p;
                }
                *(v4bf*)&Pt[w][ni * 16 + L][mi * 16 + quad * 4] = p4;
            }
            lrun[ni] += rs;
        }

        v8bf pf[4][2];
#pragma unroll
        for (int ni = 0; ni < 4; ++ni)
#pragma unroll
            for (int ki = 0; ki < 2; ++ki)
                pf[ni][ki] = *(const v8bf*)&Pt[w][ni * 16 + L][ki * 32 + quad * 8];
#pragma unroll
        for (int ma = 0; ma < 4; ++ma)
#pragma unroll
            for (int ni = 0; ni < 4; ++ni)
#pragma unroll
                for (int ki = 0; ki < 2; ++ki)
                    acc_o[ma][ni] = mfma16(vf[ma][ki], pf[ni][ki], acc_o[ma][ni]);
    }

    // fold quads: every lane gets the full row-sum for its 16 q-rows
#pragma unroll
    for (int ni = 0; ni < 4; ++ni) {
        lrun[ni] += __shfl_xor(lrun[ni], 16, 64);
        lrun[ni] += __shfl_xor(lrun[ni], 32, 64);
    }

    __syncthreads();   // B1: all Pt reads done; smem reusable

    // stage 1: every wave publishes lrun; waves 4-7 publish acc_o
    if (quad == 0) {
#pragma unroll
        for (int ni = 0; ni < 4; ++ni)
            red_l[w * 64 + ni * 16 + L] = lrun[ni];
    }
    if (w >= 4) {
#pragma unroll
        for (int ma = 0; ma < 4; ++ma)
#pragma unroll
            for (int ni = 0; ni < 4; ++ni)
#pragma unroll
                for (int r = 0; r < 4; ++r)
                    red_o[w - 4][ma * 16 + quad * 4 + r][ni * 16 + L] = acc_o[ma][ni][r];
    }
    __syncthreads();   // B2

    // stage 2: waves 0-3 fold partner wave's O; wave 4 computes 1/denom
    if (w < 4) {
#pragma unroll
        for (int ma = 0; ma < 4; ++ma)
#pragma unroll
            for (int ni = 0; ni < 4; ++ni)
#pragma unroll
                for (int r = 0; r < 4; ++r)
                    acc_o[ma][ni][r] += red_o[w][ma * 16 + quad * 4 + r][ni * 16 + L];
    } else if (w == 4) {
        float d = 0.f;
#pragma unroll
        for (int c = 0; c < 8; ++c) d += red_l[c * 64 + lane];
        invs[lane] = 1.0f / d;
    }
    __syncthreads();   // B3: stage-2 reads of red_o done

    if (w < 4) {
#pragma unroll
        for (int ma = 0; ma < 4; ++ma)
#pragma unroll
            for (int ni = 0; ni < 4; ++ni)
#pragma unroll
                for (int r = 0; r < 4; ++r)
                    red_o[w][ma * 16 + quad * 4 + r][ni * 16 + L] = acc_o[ma][ni][r];
    }
    __syncthreads();   // B4

    // final coalesced write: thread -> q = tid>>3, 8 consecutive a's
    {
        const int q  = threadIdx.x >> 3;
        const int ac = (threadIdx.x & 7) << 3;
        const float sc = invs[q];
        float* dst = out + (size_t)(b * S_DIM + qt * 64 + q) * A_DIM + ac;
#pragma unroll
        for (int i4 = 0; i4 < 2; ++i4) {
            float vv[4];
#pragma unroll
            for (int j = 0; j < 4; ++j) {
                const int a = ac + i4 * 4 + j;
                vv[j] = sc * (red_o[0][a][q] + red_o[1][a][q]
                            + red_o[2][a][q] + red_o[3][a][q]);
            }
            *(float4*)(dst + i4 * 4) = make_float4(vv[0], vv[1], vv[2], vv[3]);
        }
    }
}

// ---------------------------------------------------------------------------
extern "C" void kernel_launch(void* const* d_in, const int* in_sizes, int n_in,
                              void* d_out, int out_size, void* d_ws, size_t ws_size,
                              hipStream_t stream)
{
    const float* X  = (const float*)d_in[0];
    const float* Wk = (const float*)d_in[1];
    const float* Wq = (const float*)d_in[2];
    const float* Wv = (const float*)d_in[3];
    float* out = (float*)d_out;

    __bf16* Kb = (__bf16*)d_ws;                     // [16384][64]
    __bf16* Qb = Kb + (size_t)M_TOT * A_DIM;        // [16384][64] (x 1/8)
    __bf16* Vt = Qb + (size_t)M_TOT * A_DIM;        // [256][4096] V^T
    __bf16* Wb = Vt + (size_t)M_TOT * A_DIM;        // [192][1024]

    wconv_kernel<<<192, 256, 0, stream>>>(Wk, Wq, Wv, Wb);

    qkv_proj_mfma<<<512, 256, 0, stream>>>(X, Wb, Kb, Qb, Vt);

    dim3 g2(64, B_DIM), b2(512);
    attn_fused<<<g2, b2, 0, stream>>>(Qb, Kb, Vt, out);
}

// Round 7
// 144.553 us; speedup vs baseline: 1.1970x; 1.1970x over previous
//
#include <hip/hip_runtime.h>
#include <math.h>

#define B_DIM 4
#define S_DIM 4096
#define E_DIM 1024
#define A_DIM 64
#define M_TOT (B_DIM * S_DIM) /* 16384 */

typedef __bf16 v8bf __attribute__((ext_vector_type(8)));
typedef __bf16 v4bf __attribute__((ext_vector_type(4)));
typedef float  v4f  __attribute__((ext_vector_type(4)));

__device__ __forceinline__ v4f mfma16(v8bf a, v8bf b, v4f c) {
    return __builtin_amdgcn_mfma_f32_16x16x32_bf16(a, b, c, 0, 0, 0);
}

// async global->LDS DMA, 16B per lane.  Dest = wave-uniform base + lane*16.
__device__ __forceinline__ void lds_dma16(const void* g, void* l) {
    __builtin_amdgcn_global_load_lds(
        (const __attribute__((address_space(1))) unsigned int*)g,
        (__attribute__((address_space(3))) unsigned int*)l, 16, 0, 0);
}

// ---------------------------------------------------------------------------
// Pre-pass: fp32 weights -> bf16 Wb[192][1024] (rows 0-63 K, 64-127 Q, 128-191 V).
// ---------------------------------------------------------------------------
__global__ __launch_bounds__(256) void wconv_kernel(
    const float* __restrict__ Wk, const float* __restrict__ Wq,
    const float* __restrict__ Wv, __bf16* __restrict__ Wb)
{
    const int i = blockIdx.x * 256 + threadIdx.x;   // float4 index, 49152 total
    const int w = i >> 14;
    const int off = (i & 16383) * 4;
    const float* s = ((w == 0) ? Wk : (w == 1) ? Wq : Wv) + off;
    float4 v = *(const float4*)s;
    v4bf o;
    o[0] = (__bf16)v.x; o[1] = (__bf16)v.y; o[2] = (__bf16)v.z; o[3] = (__bf16)v.w;
    *(v4bf*)(Wb + (size_t)w * 65536 + off) = o;
}

// ---------------------------------------------------------------------------
// Fused QKV projection v13 (compile-fixed): v8's verified structure (64 rows
// x 192 cols per block, 256 blocks x 4 waves, DMA-staged B with XOR swizzle,
// LDS-staged X, identical fragment bytes + MFMA order -> bitwise-same
// result) with the T4 counted-vmcnt schedule replacing __syncthreads():
//   v8's barrier = s_waitcnt vmcnt(0) lgkmcnt(0); s_barrier  -> every chunk
//   drained ALL 16 in-flight VMEM incl. fresh HBM X loads (~900 cy).  That
//   drain is why r3/r4's occupancy changes were null (every wave stalls at
//   its OWN drain).  Now:
//     - issue loadX(kc+1) [4], fence, stageB(kc+1) [6]
//     - s_waitcnt vmcnt(10): retires exactly B[kc] (issued a full iteration
//       ago, L2-resident -> ~0 stall); X + B[kc+1] stay in flight
//     - ds_read + MFMA (X latency hides under this)
//     - flushX (compiler-inserted vmcnt(6): X done, B[kc+1] STILL flying)
//     - s_waitcnt lgkmcnt(0); s_barrier  -- NO vmcnt drain; B[kc+1] DMAs
//       cross the barrier.  Safe: B rows are wave-private (wave w DMAs and
//       reads only rows [w*48, w*48+48)).
// ---------------------------------------------------------------------------
__global__ __launch_bounds__(256) void qkv_proj_mfma(
    const float* __restrict__ X,
    const __bf16* __restrict__ Wb,   // [192][1024]
    __bf16* __restrict__ Kb,
    __bf16* __restrict__ Qb,
    __bf16* __restrict__ Vt)
{
    const int r0   = blockIdx.x * 64;
    const int w    = threadIdx.x >> 6;
    const int lane = threadIdx.x & 63;
    const int L    = lane & 15;
    const int quad = lane >> 4;
    const int cbase = w * 48;

    // Xs[2][64][72] bf16 (padded rows) | Bs[2][192][64] bf16 (DMA, swizzled)
    __shared__ __align__(16) char smem[18432 + 49152];
    __bf16* Xs = (__bf16*)smem;                  // 2 x 4608 elems
    __bf16* Bs = (__bf16*)(smem + 18432);        // 2 x 12288 elems
    float (*Tv)[65] = (float(*)[65])smem;        // epilogue union

    v4f acc[4][3]; // [mi][nt]
#pragma unroll
    for (int mi = 0; mi < 4; ++mi)
#pragma unroll
        for (int nt = 0; nt < 3; ++nt) acc[mi][nt] = (v4f){0.f, 0.f, 0.f, 0.f};

    // ---- B staging: 6 DMA issues/wave, rows [w*48, w*48+48), XOR swizzle ----
    const int brow_l  = lane >> 3;          // 0..7 within an 8-row issue
    const int bchunk  = lane & 7;           // 16B k-chunk slot
    const int bgchunk = bchunk ^ brow_l;    // fetched k-chunk (slot^row parity)
    auto stageB = [&](int kc, int buf) {
#pragma unroll
        for (int j = 0; j < 6; ++j) {
            const int rowbase = w * 48 + j * 8;
            const __bf16* g = Wb + (size_t)(rowbase + brow_l) * E_DIM
                              + kc * 64 + bgchunk * 8;
            lds_dma16(g, Bs + buf * 12288 + rowbase * 64);
        }
    };

    // ---- X staging: 4 float4/thread, coalesced (4 rows x 256B per issue) ----
    const int xrow_i = (lane >> 4);         // row within 4-row issue group
    const int xcol   = (lane & 15) * 4;     // float offset
    float4 xr[4];
    auto loadX = [&](int kc) {
#pragma unroll
        for (int i = 0; i < 4; ++i) {
            const int row = i * 16 + w * 4 + xrow_i;
            xr[i] = *(const float4*)(X + (size_t)(r0 + row) * E_DIM + kc * 64 + xcol);
        }
    };
    auto flushX = [&](int buf) {
#pragma unroll
        for (int i = 0; i < 4; ++i) {
            const int row = i * 16 + w * 4 + xrow_i;
            v4bf o;
            o[0] = (__bf16)xr[i].x; o[1] = (__bf16)xr[i].y;
            o[2] = (__bf16)xr[i].z; o[3] = (__bf16)xr[i].w;
            *(v4bf*)(Xs + buf * 4608 + row * 72 + xcol) = o;
        }
    };

    // prologue: X0 older than B0 -> compiler's flushX wait is vmcnt(6),
    // leaving B0's DMAs in flight across the first barrier.
    loadX(0);
    asm volatile("" ::: "memory");          // keep X issue-order before B
    stageB(0, 0);
    flushX(0);
    asm volatile("s_waitcnt lgkmcnt(0)" ::: "memory");
    __builtin_amdgcn_s_barrier();           // Xs[0] visible; B0 still flying

#pragma unroll 1
    for (int kc = 0; kc < 16; ++kc) {
        const int cur = kc & 1;
        if (kc < 15) {
            loadX(kc + 1);                  // +4 (older than B[kc+1])
            asm volatile("" ::: "memory");
            stageB(kc + 1, cur ^ 1);        // +6
            // retire exactly B[kc] (oldest 6); X + B[kc+1] stay in flight
            asm volatile("s_waitcnt vmcnt(10)" ::: "memory");
        } else {
            asm volatile("s_waitcnt vmcnt(0)" ::: "memory");
        }
        // ---- compute chunk kc from LDS ----
        v8bf afr[4][2];
#pragma unroll
        for (int mi = 0; mi < 4; ++mi)
#pragma unroll
            for (int ka = 0; ka < 2; ++ka)
                afr[mi][ka] = *(const v8bf*)(Xs + cur * 4608 +
                                (mi * 16 + L) * 72 + ka * 32 + quad * 8);
        v8bf bfr[3][2];
#pragma unroll
        for (int nt = 0; nt < 3; ++nt)
#pragma unroll
            for (int ka = 0; ka < 2; ++ka) {
                const int R = cbase + nt * 16 + L;
                const int slot = (ka * 4 + quad) ^ (R & 7);
                bfr[nt][ka] = *(const v8bf*)(Bs + cur * 12288 + R * 64 + slot * 8);
            }
#pragma unroll
        for (int mi = 0; mi < 4; ++mi)
#pragma unroll
            for (int nt = 0; nt < 3; ++nt)
#pragma unroll
                for (int ka = 0; ka < 2; ++ka)
                    acc[mi][nt] = mfma16(afr[mi][ka], bfr[nt][ka], acc[mi][nt]);

        if (kc < 15) flushX(cur ^ 1);       // compiler waits vmcnt(6): X only
        asm volatile("s_waitcnt lgkmcnt(0)" ::: "memory");
        __builtin_amdgcn_s_barrier();       // NO vmcnt drain: B[kc+1] crosses
    }

    // ---- epilogue: K (cols<64), Q (<128, x1/8), V (->LDS transpose) ----
#pragma unroll
    for (int nt = 0; nt < 3; ++nt) {
        const int c0 = cbase + nt * 16; // wave-uniform; tiles never straddle
        if (c0 < 64) {
#pragma unroll
            for (int mi = 0; mi < 4; ++mi)
#pragma unroll
                for (int r = 0; r < 4; ++r)
                    Kb[(size_t)(r0 + mi * 16 + quad * 4 + r) * A_DIM + c0 + L] =
                        (__bf16)acc[mi][nt][r];
        } else if (c0 < 128) {
#pragma unroll
            for (int mi = 0; mi < 4; ++mi)
#pragma unroll
                for (int r = 0; r < 4; ++r)
                    Qb[(size_t)(r0 + mi * 16 + quad * 4 + r) * A_DIM + (c0 - 64) + L] =
                        (__bf16)(acc[mi][nt][r] * 0.125f);
        } else {
#pragma unroll
            for (int mi = 0; mi < 4; ++mi)
#pragma unroll
                for (int r = 0; r < 4; ++r)
                    Tv[mi * 16 + quad * 4 + r][(c0 - 128) + L] = acc[mi][nt][r];
        }
    }
    __syncthreads();

    // transposed V write: thread t -> V-col a = t>>2, s-quarter = t&3
    {
        const int batch = r0 >> 12;
        const int s0    = r0 & 4095;
        const int a     = threadIdx.x >> 2;
        const int part  = threadIdx.x & 3;
        __bf16* vrow = Vt + (size_t)(batch * 64 + a) * S_DIM + s0 + part * 16;
#pragma unroll
        for (int h = 0; h < 2; ++h) {
            v8bf pk;
#pragma unroll
            for (int j = 0; j < 8; ++j)
                pk[j] = (__bf16)Tv[part * 16 + h * 8 + j][a];
            *(v8bf*)(vrow + h * 8) = pk;
        }
    }
}

// ---------------------------------------------------------------------------
// Causal flash attention v5 (round-1-verified, untouched):
// no split-K, no combine pass.  One 512-thread block (8 waves) per (b, qt);
// waves stride 8 over k-tiles; wave-private Pt scratch, no barriers in the
// k-loop; cross-wave l/O reduction in LDS; fp32 out written directly.
// ---------------------------------------------------------------------------
__global__ __launch_bounds__(512, 2) void attn_fused(
    const __bf16* __restrict__ Qb,
    const __bf16* __restrict__ Kb,
    const __bf16* __restrict__ Vt,
    float* __restrict__ out)
{
    const int b  = blockIdx.y;
    const int qt = blockIdx.x;              // 0..63

    const int w    = threadIdx.x >> 6;      // 0..7
    const int lane = threadIdx.x & 63;
    const int L    = lane & 15;
    const int quad = lane >> 4;

    __shared__ __align__(16) char smem[73728];
    __bf16 (*Pt)[64][72]   = (__bf16(*)[64][72])smem;          // [8][64][72] loop phase
    float*  red_l          = (float*)smem;                     // [8][64]   combine phase
    float (*red_o)[64][65] = (float(*)[64][65])(smem + 2048);  // [4][64][65]
    float*  invs           = (float*)(smem + 2048 + 66560);    // [64]

    v8bf qf[4][2];
#pragma unroll
    for (int ni = 0; ni < 4; ++ni)
#pragma unroll
        for (int ka = 0; ka < 2; ++ka)
            qf[ni][ka] = *(const v8bf*)(Qb +
                (size_t)(b * S_DIM + qt * 64 + ni * 16 + L) * A_DIM + ka * 32 + quad * 8);

    v4f acc_o[4][4];
#pragma unroll
    for (int i = 0; i < 4; ++i)
#pragma unroll
        for (int j = 0; j < 4; ++j) acc_o[i][j] = (v4f){0.f, 0.f, 0.f, 0.f};
    float lrun[4] = {0.f, 0.f, 0.f, 0.f};

    for (int kt = w; kt <= qt; kt += 8) {
        v8bf kf[4][2];
#pragma unroll
        for (int mi = 0; mi < 4; ++mi)
#pragma unroll
            for (int ka = 0; ka < 2; ++ka)
                kf[mi][ka] = *(const v8bf*)(Kb +
                    (size_t)(b * S_DIM + kt * 64 + mi * 16 + L) * A_DIM + ka * 32 + quad * 8);
        v8bf vf[4][2];
#pragma unroll
        for (int ma = 0; ma < 4; ++ma)
#pragma unroll
            for (int ki = 0; ki < 2; ++ki)
                vf[ma][ki] = *(const v8bf*)(Vt +
                    (size_t)(b * 64 + ma * 16 + L) * S_DIM + kt * 64 + ki * 32 + quad * 8);

        const bool diag = (kt == qt);

#pragma unroll
        for (int ni = 0; ni < 4; ++ni) {
            v4f s[4];
#pragma unroll
            for (int mi = 0; mi < 4; ++mi) s[mi] = (v4f){0.f, 0.f, 0.f, 0.f};
#pragma unroll
            for (int mi = 0; mi < 4; ++mi)
#pragma unroll
                for (int ka = 0; ka < 2; ++ka)
                    s[mi] = mfma16(kf[mi][ka], qf[ni][ka], s[mi]);

            float rs = 0.f;
#pragma unroll
            for (int mi = 0; mi < 4; ++mi) {
                v4bf p4;
#pragma unroll
                for (int r = 0; r < 4; ++r) {
                    const bool masked = diag && (mi * 16 + quad * 4 + r > ni * 16 + L);
                    const float p = masked ? 0.f : __expf(s[mi][r]);
                    rs += p;
                    p4[r] = (__bf16)p;
                }
                *(v4bf*)&Pt[w][ni * 16 + L][mi * 16 + quad * 4] = p4;
            }
            lrun[ni] += rs;
        }

        v8bf pf[4][2];
#pragma unroll
        for (int ni = 0; ni < 4; ++ni)
#pragma unroll
            for (int ki = 0; ki < 2; ++ki)
                pf[ni][ki] = *(const v8bf*)&Pt[w][ni * 16 + L][ki * 32 + quad * 8];
#pragma unroll
        for (int ma = 0; ma < 4; ++ma)
#pragma unroll
            for (int ni = 0; ni < 4; ++ni)
#pragma unroll
                for (int ki = 0; ki < 2; ++ki)
                    acc_o[ma][ni] = mfma16(vf[ma][ki], pf[ni][ki], acc_o[ma][ni]);
    }

    // fold quads: every lane gets the full row-sum for its 16 q-rows
#pragma unroll
    for (int ni = 0; ni < 4; ++ni) {
        lrun[ni] += __shfl_xor(lrun[ni], 16, 64);
        lrun[ni] += __shfl_xor(lrun[ni], 32, 64);
    }

    __syncthreads();   // B1: all Pt reads done; smem reusable

    // stage 1: every wave publishes lrun; waves 4-7 publish acc_o
    if (quad == 0) {
#pragma unroll
        for (int ni = 0; ni < 4; ++ni)
            red_l[w * 64 + ni * 16 + L] = lrun[ni];
    }
    if (w >= 4) {
#pragma unroll
        for (int ma = 0; ma < 4; ++ma)
#pragma unroll
            for (int ni = 0; ni < 4; ++ni)
#pragma unroll
                for (int r = 0; r < 4; ++r)
                    red_o[w - 4][ma * 16 + quad * 4 + r][ni * 16 + L] = acc_o[ma][ni][r];
    }
    __syncthreads();   // B2

    // stage 2: waves 0-3 fold partner wave's O; wave 4 computes 1/denom
    if (w < 4) {
#pragma unroll
        for (int ma = 0; ma < 4; ++ma)
#pragma unroll
            for (int ni = 0; ni < 4; ++ni)
#pragma unroll
                for (int r = 0; r < 4; ++r)
                    acc_o[ma][ni][r] += red_o[w][ma * 16 + quad * 4 + r][ni * 16 + L];
    } else if (w == 4) {
        float d = 0.f;
#pragma unroll
        for (int c = 0; c < 8; ++c) d += red_l[c * 64 + lane];
        invs[lane] = 1.0f / d;
    }
    __syncthreads();   // B3: stage-2 reads of red_o done

    if (w < 4) {
#pragma unroll
        for (int ma = 0; ma < 4; ++ma)
#pragma unroll
            for (int ni = 0; ni < 4; ++ni)
#pragma unroll
                for (int r = 0; r < 4; ++r)
                    red_o[w][ma * 16 + quad * 4 + r][ni * 16 + L] = acc_o[ma][ni][r];
    }
    __syncthreads();   // B4

    // final coalesced write: thread -> q = tid>>3, 8 consecutive a's
    {
        const int q  = threadIdx.x >> 3;
        const int ac = (threadIdx.x & 7) << 3;
        const float sc = invs[q];
        float* dst = out + (size_t)(b * S_DIM + qt * 64 + q) * A_DIM + ac;
#pragma unroll
        for (int i4 = 0; i4 < 2; ++i4) {
            float vv[4];
#pragma unroll
            for (int j = 0; j < 4; ++j) {
                const int a = ac + i4 * 4 + j;
                vv[j] = sc * (red_o[0][a][q] + red_o[1][a][q]
                            + red_o[2][a][q] + red_o[3][a][q]);
            }
            *(float4*)(dst + i4 * 4) = make_float4(vv[0], vv[1], vv[2], vv[3]);
        }
    }
}

// ---------------------------------------------------------------------------
extern "C" void kernel_launch(void* const* d_in, const int* in_sizes, int n_in,
                              void* d_out, int out_size, void* d_ws, size_t ws_size,
                              hipStream_t stream)
{
    const float* X  = (const float*)d_in[0];
    const float* Wk = (const float*)d_in[1];
    const float* Wq = (const float*)d_in[2];
    const float* Wv = (const float*)d_in[3];
    float* out = (float*)d_out;

    __bf16* Kb = (__bf16*)d_ws;                     // [16384][64]
    __bf16* Qb = Kb + (size_t)M_TOT * A_DIM;        // [16384][64] (x 1/8)
    __bf16* Vt = Qb + (size_t)M_TOT * A_DIM;        // [256][4096] V^T
    __bf16* Wb = Vt + (size_t)M_TOT * A_DIM;        // [192][1024]

    wconv_kernel<<<192, 256, 0, stream>>>(Wk, Wq, Wv, Wb);

    qkv_proj_mfma<<<256, 256, 0, stream>>>(X, Wb, Kb, Qb, Vt);

    dim3 g2(64, B_DIM), b2(512);
    attn_fused<<<g2, b2, 0, stream>>>(Qb, Kb, Vt, out);
}